// Round 10
// baseline (195.925 us; speedup 1.0000x reference)
//
#include <hip/hip_runtime.h>

constexpr int CIN = 768;
constexpr int CD  = 32;
constexpr int NE  = 8192;
constexpr int M   = 16384;      // B*N = 64*256
constexpr int SCH = 64;         // code chunks for argmin
constexpr int CPC = NE / SCH;   // 128 codes per chunk
constexpr int PTB = 256;        // points per argmin block (4 waves x 64)
#define MARGIN 0.004f

typedef short short8 __attribute__((ext_vector_type(8)));
typedef float f32x4  __attribute__((ext_vector_type(4)));

// RNE split of fp32 into bf16 hi + bf16 lo-residual
__device__ inline void split_bf16(float x, unsigned short& h, unsigned short& l) {
  unsigned u = __float_as_uint(x);
  unsigned hb = (u + 0x7FFFu + ((u >> 16) & 1u)) >> 16;
  float hf = __uint_as_float(hb << 16);
  float r = x - hf;
  unsigned u2 = __float_as_uint(r);
  unsigned lb = (u2 + 0x7FFFu + ((u2 >> 16) & 1u)) >> 16;
  h = (unsigned short)hb;
  l = (unsigned short)lb;
}

__device__ inline void gload_lds16(const void* g, void* l) {
  __builtin_amdgcn_global_load_lds(
      (const __attribute__((address_space(1))) unsigned int*)g,
      (__attribute__((address_space(3))) unsigned int*)l, 16, 0, 0);
}

// ---------------- k_split: parallel transpose-splits of Wc and We (1 elem/thread) ----
__global__ __launch_bounds__(256) void k_split(
    const float* __restrict__ Wc, const float* __restrict__ We,
    unsigned short* __restrict__ WcTh, unsigned short* __restrict__ WcTl,
    unsigned short* __restrict__ WeTh, unsigned short* __restrict__ WeTl) {
  const int t = threadIdx.x;
  if (blockIdx.x < 96) {
    const int idx = blockIdx.x * 256 + t;      // Wc [768][32]
    const int k = idx >> 5, n = idx & 31;
    unsigned short h, l;
    split_bf16(Wc[idx], h, l);
    WcTh[n * CIN + k] = h;
    WcTl[n * CIN + k] = l;
  } else {
    const int idx = (blockIdx.x - 96) * 256 + t;   // We [32][768]
    const int k = idx / CIN, n = idx - k * CIN;
    unsigned short h, l;
    split_bf16(We[idx], h, l);
    WeTh[n * CD + k] = h;
    WeTl[n * CD + k] = l;
  }
}

// ---------------- k_main: compress (0..1023, MFMA) + codebook (1024..2047, VALU) ------
__global__ __launch_bounds__(256) void k_main(
    const float* __restrict__ z,
    const unsigned short* __restrict__ WcTh, const unsigned short* __restrict__ WcTl,
    const float* __restrict__ bc,
    const float* __restrict__ emb, const float* __restrict__ Wct,
    const float* __restrict__ bct,
    float* __restrict__ zc, unsigned short* __restrict__ zh,
    unsigned short* __restrict__ zl,
    float* __restrict__ cb, float* __restrict__ cbT, float* __restrict__ cnorm,
    unsigned short* __restrict__ ch, unsigned short* __restrict__ cl) {
  __shared__ float smem[1632];
  const int t = threadIdx.x;
  if (blockIdx.x >= 1024) {
    // ---- codebook = emb @ W_ct + b_ct (+ cbT transpose for rescue) ----
    for (int i = t; i < CD * CD; i += 256) smem[i] = Wct[i];
    __syncthreads();
    const int g   = (blockIdx.x - 1024) * 256 + t;
    const int row = g >> 5;
    const int col = g & 31;
    float acc = bct[col];
    const float* er = emb + row * CD;
    #pragma unroll
    for (int k = 0; k < CD; ++k) acc = fmaf(er[k], smem[k * CD + col], acc);
    cb[g] = acc;
    cbT[(long)col * NE + row] = acc;
    unsigned short h, l;
    split_bf16(acc, h, l);
    ch[g] = h; cl[g] = l;
    float v = acc * acc;
    #pragma unroll
    for (int m = 16; m >= 1; m >>= 1) v += __shfl_xor(v, m, 64);
    if (col == 0) cnorm[row] = v;
    return;
  }
  // ---- zc = z @ W_compress + b via split-bf16 MFMA; block = 16 rows, K-split x4 ----
  float* ps = smem;
  const int lane = t & 63;
  const int wv   = t >> 6;                    // K-split 0..3
  const int n    = lane & 15;
  const int quad = lane >> 4;
  const int r0   = blockIdx.x * 16;

  const float* za = z + (long)(r0 + n) * CIN + wv * 192 + quad * 8;
  const unsigned short* bh0 = WcTh + n * CIN + wv * 192 + quad * 8;
  const unsigned short* bl0 = WcTl + n * CIN + wv * 192 + quad * 8;
  const unsigned short* bh1 = bh0 + 16 * CIN;
  const unsigned short* bl1 = bl0 + 16 * CIN;

  float4 zbuf[12];
  #pragma unroll
  for (int kt = 0; kt < 6; ++kt) {
    zbuf[2 * kt]     = *(const float4*)(za + kt * 32);
    zbuf[2 * kt + 1] = *(const float4*)(za + kt * 32 + 4);
  }

  f32x4 acc0, acc1;
  if (wv == 0) {
    const float b0 = bc[n];
    const float b1 = bc[n + 16];
    acc0 = (f32x4){b0, b0, b0, b0};
    acc1 = (f32x4){b1, b1, b1, b1};
  } else {
    acc0 = (f32x4){0.f, 0.f, 0.f, 0.f};
    acc1 = (f32x4){0.f, 0.f, 0.f, 0.f};
  }

  #pragma unroll
  for (int kt = 0; kt < 6; ++kt) {            // 6 K-tiles of 32 per wave
    const float4 za0 = zbuf[2 * kt];
    const float4 za1 = zbuf[2 * kt + 1];
    short8 Ah, Al;
    {
      unsigned short h, l;
      split_bf16(za0.x, h, l); Ah[0] = (short)h; Al[0] = (short)l;
      split_bf16(za0.y, h, l); Ah[1] = (short)h; Al[1] = (short)l;
      split_bf16(za0.z, h, l); Ah[2] = (short)h; Al[2] = (short)l;
      split_bf16(za0.w, h, l); Ah[3] = (short)h; Al[3] = (short)l;
      split_bf16(za1.x, h, l); Ah[4] = (short)h; Al[4] = (short)l;
      split_bf16(za1.y, h, l); Ah[5] = (short)h; Al[5] = (short)l;
      split_bf16(za1.z, h, l); Ah[6] = (short)h; Al[6] = (short)l;
      split_bf16(za1.w, h, l); Ah[7] = (short)h; Al[7] = (short)l;
    }
    const short8 Bh0 = *(const short8*)(bh0 + kt * 32);
    const short8 Bl0 = *(const short8*)(bl0 + kt * 32);
    const short8 Bh1 = *(const short8*)(bh1 + kt * 32);
    const short8 Bl1 = *(const short8*)(bl1 + kt * 32);
    acc0 = __builtin_amdgcn_mfma_f32_16x16x32_bf16(Ah, Bh0, acc0, 0, 0, 0);
    acc0 = __builtin_amdgcn_mfma_f32_16x16x32_bf16(Ah, Bl0, acc0, 0, 0, 0);
    acc0 = __builtin_amdgcn_mfma_f32_16x16x32_bf16(Al, Bh0, acc0, 0, 0, 0);
    acc1 = __builtin_amdgcn_mfma_f32_16x16x32_bf16(Ah, Bh1, acc1, 0, 0, 0);
    acc1 = __builtin_amdgcn_mfma_f32_16x16x32_bf16(Ah, Bl1, acc1, 0, 0, 0);
    acc1 = __builtin_amdgcn_mfma_f32_16x16x32_bf16(Al, Bh1, acc1, 0, 0, 0);
  }

  if (wv != 0) {
    float* pp = ps + (wv - 1) * 544;
    #pragma unroll
    for (int r = 0; r < 4; ++r) {
      const int row = quad * 4 + r;
      pp[row * 17 + n]       = acc0[r];
      pp[272 + row * 17 + n] = acc1[r];
    }
  }
  __syncthreads();
  if (wv == 0) {
    #pragma unroll
    for (int r = 0; r < 4; ++r) {
      const int row = quad * 4 + r;
      const float v0 = ((acc0[r] + ps[row * 17 + n]) + ps[544 + row * 17 + n])
                       + ps[1088 + row * 17 + n];
      const float v1 = ((acc1[r] + ps[272 + row * 17 + n]) + ps[816 + row * 17 + n])
                       + ps[1360 + row * 17 + n];
      const long i0 = (long)(r0 + row) * CD + n;
      zc[i0]      = v0;
      zc[i0 + 16] = v1;
      unsigned short h, l;
      split_bf16(-2.f * v0, h, l); zh[i0] = h;      zl[i0] = l;
      split_bf16(-2.f * v1, h, l); zh[i0 + 16] = h; zl[i0 + 16] = l;
    }
  }
}

// ---------------- MFMA approx distances + per-chunk min ----------------
// 2 chunks staged per block (32 KB) behind ONE barrier; A fragments reused.
__global__ __launch_bounds__(256) void k_argmin(
    const unsigned short* __restrict__ zh, const unsigned short* __restrict__ zl,
    const unsigned short* __restrict__ ch, const unsigned short* __restrict__ cl,
    const float* __restrict__ cnorm,
    float* __restrict__ pd) {
  __shared__ __align__(16) unsigned short chs[2][CPC * CD];   // 16 KB
  __shared__ __align__(16) unsigned short cls[2][CPC * CD];   // 16 KB
  const int pb   = blockIdx.x & (M / PTB - 1);   // 0..63
  const int cp   = blockIdx.x >> 6;              // 0..31 chunk-pair
  const int cid0 = cp * 2;
  const int lane = threadIdx.x & 63;
  const int wv   = threadIdx.x >> 6;
  const int col  = lane & 15;
  const int quad = lane >> 4;
  const int p0   = pb * PTB + wv * 64;

  const char* chg = (const char*)ch + (long)cid0 * (CPC * CD * 2);
  const char* clg = (const char*)cl + (long)cid0 * (CPC * CD * 2);
  #pragma unroll
  for (int s = 0; s < 4; ++s) {
    const int lo = s * 4096 + wv * 1024;
    gload_lds16(chg + lo + lane * 16, (char*)chs + lo);
    gload_lds16(clg + lo + lane * 16, (char*)cls + lo);
  }

  short8 Ah[4], Al[4];
  #pragma unroll
  for (int s = 0; s < 4; ++s) {
    Ah[s] = *(const short8*)(zh + (long)(p0 + s * 16 + col) * CD + quad * 8);
    Al[s] = *(const short8*)(zl + (long)(p0 + s * 16 + col) * CD + quad * 8);
  }

  float cnv[2][8];
  #pragma unroll
  for (int c2 = 0; c2 < 2; ++c2) {
    const int jb = (cid0 + c2) * CPC;
    #pragma unroll
    for (int tt = 0; tt < 8; ++tt) cnv[c2][tt] = cnorm[jb + tt * 16 + col];
  }

  __syncthreads();   // drains global_load_lds (vmcnt) + A/cnv loads

  #pragma unroll
  for (int c2 = 0; c2 < 2; ++c2) {
    float bd[4][4];
    #pragma unroll
    for (int s = 0; s < 4; ++s)
      #pragma unroll
      for (int r = 0; r < 4; ++r) bd[s][r] = 1e30f;

    #pragma unroll
    for (int tt = 0; tt < 8; ++tt) {           // 8 tiles of 16 codes from LDS
      const short8 Bh = *(const short8*)(&chs[c2][(tt * 16 + col) * CD + quad * 8]);
      const short8 Bl = *(const short8*)(&cls[c2][(tt * 16 + col) * CD + quad * 8]);
      const f32x4 c4 = {cnv[c2][tt], cnv[c2][tt], cnv[c2][tt], cnv[c2][tt]};
      #pragma unroll
      for (int s = 0; s < 4; ++s) {
        f32x4 g = __builtin_amdgcn_mfma_f32_16x16x32_bf16(Ah[s], Bh, c4, 0, 0, 0);
        g = __builtin_amdgcn_mfma_f32_16x16x32_bf16(Ah[s], Bl, g, 0, 0, 0);
        g = __builtin_amdgcn_mfma_f32_16x16x32_bf16(Al[s], Bh, g, 0, 0, 0);
        #pragma unroll
        for (int r = 0; r < 4; ++r) bd[s][r] = fminf(bd[s][r], g[r]);
      }
    }

    #pragma unroll
    for (int mm = 1; mm <= 8; mm <<= 1) {
      #pragma unroll
      for (int s = 0; s < 4; ++s)
        #pragma unroll
        for (int r = 0; r < 4; ++r)
          bd[s][r] = fminf(bd[s][r], __shfl_xor(bd[s][r], mm, 64));
    }
    if (col == 0) {
      #pragma unroll
      for (int s = 0; s < 4; ++s)
        #pragma unroll
        for (int r = 0; r < 4; ++r) {
          const int pA = p0 + s * 16 + quad * 4 + r;
          pd[(long)pA * SCH + cid0 + c2] = bd[s][r];
        }
    }
  }
}

// ---------------- exact-fp32 rescue over transposed codebook (coalesced scan) --------
__global__ __launch_bounds__(256) void k_rescue(
    const float* __restrict__ zc, const float* __restrict__ cb,
    const float* __restrict__ cbT, const float* __restrict__ cnorm,
    const float* __restrict__ pd,
    float* __restrict__ zq, unsigned short* __restrict__ zqh,
    unsigned short* __restrict__ zql, float* __restrict__ lpart) {
  const int lane = threadIdx.x & 63;
  const int wv   = threadIdx.x >> 6;
  const int p    = blockIdx.x * 4 + wv;

  const float m = pd[(long)p * SCH + lane];
  float dstar = m;
  #pragma unroll
  for (int mm = 1; mm <= 32; mm <<= 1) dstar = fminf(dstar, __shfl_xor(dstar, mm, 64));
  unsigned long long mask = __ballot(m <= dstar + MARGIN);

  float zr[CD];
  {
    const float4* z4 = (const float4*)(zc + (long)p * CD);
    #pragma unroll
    for (int q = 0; q < 8; ++q) {
      float4 v = z4[q];
      zr[4 * q + 0] = v.x; zr[4 * q + 1] = v.y; zr[4 * q + 2] = v.z; zr[4 * q + 3] = v.w;
    }
  }

  float bd = 1e30f;
  int   bj = 0x7fffffff;
  while (mask) {
    const int c = (int)__builtin_ctzll(mask);
    mask &= mask - 1;
    const int j0 = c * CPC + 2 * lane;
    const float* cp = cbT + j0;
    float acc0 = 0.f, acc1 = 0.f;
    #pragma unroll
    for (int k = 0; k < CD; ++k) {
      const float2 cv = *(const float2*)(cp + (long)k * NE);
      acc0 = fmaf(zr[k], cv.x, acc0);
      acc1 = fmaf(zr[k], cv.y, acc1);
    }
    const float2 cn = *(const float2*)(cnorm + j0);
    const float d0 = fmaf(-2.f, acc0, cn.x);
    const float d1 = fmaf(-2.f, acc1, cn.y);
    if (d0 < bd) { bd = d0; bj = j0; }
    if (d1 < bd) { bd = d1; bj = j0 + 1; }
  }
  #pragma unroll
  for (int mm = 1; mm <= 32; mm <<= 1) {
    const float od = __shfl_xor(bd, mm, 64);
    const int   oj = __shfl_xor(bj, mm, 64);
    if (od < bd || (od == bd && oj < bj)) { bd = od; bj = oj; }
  }

  float ls = 0.f;
  if (lane < 32) {
    const float cv = cb[(long)bj * CD + lane];
    const float zv = zc[(long)p * CD + lane];
    zq[(long)p * CD + lane] = cv;
    unsigned short hh, ll;
    split_bf16(cv, hh, ll);
    zqh[(long)p * CD + lane] = hh;
    zql[(long)p * CD + lane] = ll;
    const float df = cv - zv;
    ls = df * df;
  }
  #pragma unroll
  for (int mm = 1; mm <= 32; mm <<= 1) ls += __shfl_xor(ls, mm, 64);
  if (lane == 0) lpart[p] = ls;
}

// ---------------- out = z_q @ W_expand + b_expand via split-bf16 MFMA ----------------
// 3072 blocks: block = 16 rows x 256 cols (4 waves x 4 tiles), ONE LDS park +
// barrier, then per-row 1-KB contiguous float4 stores. 3x TLP vs the 1024-block
// 2-phase version; store values bit-identical.
__global__ __launch_bounds__(256) void k_expand(
    const unsigned short* __restrict__ zqh, const unsigned short* __restrict__ zql,
    const unsigned short* __restrict__ WeTh, const unsigned short* __restrict__ WeTl,
    const float* __restrict__ be,
    const float* __restrict__ lpart,
    float* __restrict__ out,
    float* __restrict__ out_loss) {
  __shared__ float ob[16][260];
  __shared__ double redd[4];
  const int t = threadIdx.x;
  if (blockIdx.x == 3072) {
    double v = 0.0;
    for (int k = t; k < M; k += 256) v += (double)lpart[k];
    #pragma unroll
    for (int mm = 1; mm <= 32; mm <<= 1) v += __shfl_xor(v, mm, 64);
    if ((t & 63) == 0) redd[t >> 6] = v;
    __syncthreads();
    if (t == 0)
      out_loss[0] = (float)(3.0 * (redd[0] + redd[1] + redd[2] + redd[3]) / (double)(M * CD));
    return;
  }
  const int lane = t & 63;
  const int wv   = t >> 6;
  const int col  = lane & 15;
  const int quad = lane >> 4;
  const int rb   = blockIdx.x & 1023;      // row-block 0..1023
  const int cg   = blockIdx.x >> 10;       // col-group 0..2
  const int r0   = rb * 16;

  const short8 Ah = *(const short8*)(zqh + (long)(r0 + col) * CD + quad * 8);
  const short8 Al = *(const short8*)(zql + (long)(r0 + col) * CD + quad * 8);

  #pragma unroll
  for (int tt = 0; tt < 4; ++tt) {
    const int n0 = cg * 256 + wv * 64 + tt * 16;
    const short8 Bh = *(const short8*)(WeTh + (long)(n0 + col) * CD + quad * 8);
    const short8 Bl = *(const short8*)(WeTl + (long)(n0 + col) * CD + quad * 8);
    const float bv = be[n0 + col];
    const f32x4 c4 = {bv, bv, bv, bv};
    f32x4 g = __builtin_amdgcn_mfma_f32_16x16x32_bf16(Ah, Bh, c4, 0, 0, 0);
    g = __builtin_amdgcn_mfma_f32_16x16x32_bf16(Ah, Bl, g, 0, 0, 0);
    g = __builtin_amdgcn_mfma_f32_16x16x32_bf16(Al, Bh, g, 0, 0, 0);
    #pragma unroll
    for (int r = 0; r < 4; ++r)
      ob[quad * 4 + r][wv * 64 + tt * 16 + col] = g[r];
  }
  __syncthreads();
  #pragma unroll
  for (int i = 0; i < 4; ++i) {
    const int f   = t + i * 256;             // 0..1023 float4 slots
    const int row = f >> 6;                  // 0..15
    const int c4  = f & 63;                  // 0..63
    *(float4*)(out + (long)(r0 + row) * CIN + cg * 256 + c4 * 4) =
        *(const float4*)(&ob[row][c4 * 4]);
  }
}

extern "C" void kernel_launch(void* const* d_in, const int* in_sizes, int n_in,
                              void* d_out, int out_size, void* d_ws, size_t ws_size,
                              hipStream_t stream) {
  const float* z   = (const float*)d_in[0];
  const float* emb = (const float*)d_in[1];
  const float* Wc  = (const float*)d_in[2];
  const float* bc  = (const float*)d_in[3];
  const float* Wct = (const float*)d_in[4];
  const float* bct = (const float*)d_in[5];
  const float* We  = (const float*)d_in[6];
  const float* be  = (const float*)d_in[7];
  float* out = (float*)d_out;

  float* cb    = (float*)d_ws;              // NE*CD        = 262144 f
  float* cnorm = cb + NE * CD;              // NE           = 8192 f
  float* zc    = cnorm + NE;                // M*CD         = 524288 f
  float* zq    = zc + M * CD;               // M*CD         = 524288 f
  float* pd    = zq + M * CD;               // M*SCH        = 1048576 f
  float* lpart = pd + (long)M * SCH;        // M            = 16384 f
  unsigned short* zh   = (unsigned short*)(lpart + M);   // M*CD ush
  unsigned short* zl   = zh + M * CD;
  unsigned short* ch   = zl + M * CD;       // NE*CD ush
  unsigned short* cl   = ch + NE * CD;
  unsigned short* zqh  = cl + NE * CD;      // M*CD ush
  unsigned short* zql  = zqh + M * CD;
  unsigned short* WeTh = zql + M * CD;      // CIN*CD ush
  unsigned short* WeTl = WeTh + CIN * CD;
  unsigned short* WcTh = WeTl + CIN * CD;   // CD*CIN ush
  unsigned short* WcTl = WcTh + CIN * CD;
  float* cbT = (float*)(WcTl + CIN * CD);   // CD*NE = 262144 f

  k_split<<<192, 256, 0, stream>>>(Wc, We, WcTh, WcTl, WeTh, WeTl);
  k_main<<<2048, 256, 0, stream>>>(z, WcTh, WcTl, bc, emb, Wct, bct,
                                   zc, zh, zl, cb, cbT, cnorm, ch, cl);
  k_argmin<<<(M / PTB) * (SCH / 2), 256, 0, stream>>>(zh, zl, ch, cl, cnorm, pd);
  k_rescue<<<M / 4, 256, 0, stream>>>(zc, cb, cbT, cnorm, pd, zq, zqh, zql, lpart);
  k_expand<<<3072 + 1, 256, 0, stream>>>(zqh, zql, WeTh, WeTl, be, lpart,
                                         out, out + (long)M * CIN);
}

// Round 11
// 188.490 us; speedup vs baseline: 1.0394x; 1.0394x over previous
//
#include <hip/hip_runtime.h>

constexpr int CIN = 768;
constexpr int CD  = 32;
constexpr int NE  = 8192;
constexpr int M   = 16384;      // B*N = 64*256
constexpr int SCH = 64;         // code chunks for argmin
constexpr int CPC = NE / SCH;   // 128 codes per chunk
constexpr int PTB = 256;        // points per argmin block (4 waves x 64)
#define MARGIN 0.004f

typedef short short8 __attribute__((ext_vector_type(8)));
typedef float f32x4  __attribute__((ext_vector_type(4)));

// RNE split of fp32 into bf16 hi + bf16 lo-residual
__device__ inline void split_bf16(float x, unsigned short& h, unsigned short& l) {
  unsigned u = __float_as_uint(x);
  unsigned hb = (u + 0x7FFFu + ((u >> 16) & 1u)) >> 16;
  float hf = __uint_as_float(hb << 16);
  float r = x - hf;
  unsigned u2 = __float_as_uint(r);
  unsigned lb = (u2 + 0x7FFFu + ((u2 >> 16) & 1u)) >> 16;
  h = (unsigned short)hb;
  l = (unsigned short)lb;
}

__device__ inline void gload_lds16(const void* g, void* l) {
  __builtin_amdgcn_global_load_lds(
      (const __attribute__((address_space(1))) unsigned int*)g,
      (__attribute__((address_space(3))) unsigned int*)l, 16, 0, 0);
}

// ---------------- k_main: compress (0..1023, MFMA) + codebook/WeT (1024..2047) --------
// k_split is gone: compress gathers Wc fp32 from L2 and splits in-register
// (identical RNE bits -> zc bit-identical); codebook blocks emit WeT (24 elems
// each, parallel) and cbT via LDS transpose staging (same values, coalesced).
__global__ __launch_bounds__(256) void k_main(
    const float* __restrict__ z, const float* __restrict__ Wc,
    const float* __restrict__ bc,
    const float* __restrict__ emb, const float* __restrict__ Wct,
    const float* __restrict__ bct, const float* __restrict__ We,
    float* __restrict__ zc, unsigned short* __restrict__ zh,
    unsigned short* __restrict__ zl,
    float* __restrict__ cb, float* __restrict__ cbT, float* __restrict__ cnorm,
    unsigned short* __restrict__ ch, unsigned short* __restrict__ cl,
    unsigned short* __restrict__ WeTh, unsigned short* __restrict__ WeTl) {
  __shared__ float smem[1632];
  const int t = threadIdx.x;
  if (blockIdx.x >= 1024) {
    const int bco = blockIdx.x - 1024;
    // ---- WeT split: 24 elements per block, fully parallel ----
    if (t < 24) {
      const int idx = bco * 24 + t;          // 0..24575 over We [32][768]
      const int k = idx / CIN, nn = idx - k * CIN;
      unsigned short h, l;
      split_bf16(We[idx], h, l);
      WeTh[nn * CD + k] = h;
      WeTl[nn * CD + k] = l;
    }
    // ---- codebook = emb @ W_ct + b_ct ----
    for (int i = t; i < CD * CD; i += 256) smem[i] = Wct[i];
    __syncthreads();
    const int g   = bco * 256 + t;
    const int row = g >> 5;
    const int col = g & 31;
    float acc = bct[col];
    const float* er = emb + row * CD;
    #pragma unroll
    for (int k = 0; k < CD; ++k) acc = fmaf(er[k], smem[k * CD + col], acc);
    cb[g] = acc;
    unsigned short h, l;
    split_bf16(acc, h, l);
    ch[g] = h; cl[g] = l;
    float v = acc * acc;
    #pragma unroll
    for (int m = 16; m >= 1; m >>= 1) v += __shfl_xor(v, m, 64);
    if (col == 0) cnorm[row] = v;
    // ---- cbT via LDS transpose staging (32x9 pad -> 2-way-free banks) ----
    smem[1024 + col * 9 + (t >> 5)] = acc;
    __syncthreads();
    {
      const int tc = t >> 3;                 // 0..31 column
      const int tr = t & 7;                  // 0..7 row-in-block
      cbT[(long)tc * NE + bco * 8 + tr] = smem[1024 + tc * 9 + tr];
    }
    return;
  }
  // ---- zc = z @ W_compress + b via split-bf16 MFMA; block = 16 rows, K-split x4 ----
  float* ps = smem;
  const int lane = t & 63;
  const int wv   = t >> 6;                    // K-split 0..3
  const int n    = lane & 15;
  const int quad = lane >> 4;
  const int r0   = blockIdx.x * 16;

  const float* za = z + (long)(r0 + n) * CIN + wv * 192 + quad * 8;

  float4 zbuf[12];
  #pragma unroll
  for (int kt = 0; kt < 6; ++kt) {
    zbuf[2 * kt]     = *(const float4*)(za + kt * 32);
    zbuf[2 * kt + 1] = *(const float4*)(za + kt * 32 + 4);
  }

  f32x4 acc0, acc1;
  if (wv == 0) {
    const float b0 = bc[n];
    const float b1 = bc[n + 16];
    acc0 = (f32x4){b0, b0, b0, b0};
    acc1 = (f32x4){b1, b1, b1, b1};
  } else {
    acc0 = (f32x4){0.f, 0.f, 0.f, 0.f};
    acc1 = (f32x4){0.f, 0.f, 0.f, 0.f};
  }

  #pragma unroll
  for (int kt = 0; kt < 6; ++kt) {            // 6 K-tiles of 32 per wave
    const float4 za0 = zbuf[2 * kt];
    const float4 za1 = zbuf[2 * kt + 1];
    short8 Ah, Al;
    {
      unsigned short h, l;
      split_bf16(za0.x, h, l); Ah[0] = (short)h; Al[0] = (short)l;
      split_bf16(za0.y, h, l); Ah[1] = (short)h; Al[1] = (short)l;
      split_bf16(za0.z, h, l); Ah[2] = (short)h; Al[2] = (short)l;
      split_bf16(za0.w, h, l); Ah[3] = (short)h; Al[3] = (short)l;
      split_bf16(za1.x, h, l); Ah[4] = (short)h; Al[4] = (short)l;
      split_bf16(za1.y, h, l); Ah[5] = (short)h; Al[5] = (short)l;
      split_bf16(za1.z, h, l); Ah[6] = (short)h; Al[6] = (short)l;
      split_bf16(za1.w, h, l); Ah[7] = (short)h; Al[7] = (short)l;
    }
    // gather-split B from fp32 Wc (L2-resident; 16-lane groups hit 64-B segments)
    const int kb = wv * 192 + kt * 32 + quad * 8;
    short8 Bh0, Bl0, Bh1, Bl1;
    #pragma unroll
    for (int j = 0; j < 8; ++j) {
      unsigned short h, l;
      split_bf16(Wc[(kb + j) * CD + n], h, l);
      Bh0[j] = (short)h; Bl0[j] = (short)l;
      split_bf16(Wc[(kb + j) * CD + n + 16], h, l);
      Bh1[j] = (short)h; Bl1[j] = (short)l;
    }
    acc0 = __builtin_amdgcn_mfma_f32_16x16x32_bf16(Ah, Bh0, acc0, 0, 0, 0);
    acc0 = __builtin_amdgcn_mfma_f32_16x16x32_bf16(Ah, Bl0, acc0, 0, 0, 0);
    acc0 = __builtin_amdgcn_mfma_f32_16x16x32_bf16(Al, Bh0, acc0, 0, 0, 0);
    acc1 = __builtin_amdgcn_mfma_f32_16x16x32_bf16(Ah, Bh1, acc1, 0, 0, 0);
    acc1 = __builtin_amdgcn_mfma_f32_16x16x32_bf16(Ah, Bl1, acc1, 0, 0, 0);
    acc1 = __builtin_amdgcn_mfma_f32_16x16x32_bf16(Al, Bh1, acc1, 0, 0, 0);
  }

  if (wv != 0) {
    float* pp = ps + (wv - 1) * 544;
    #pragma unroll
    for (int r = 0; r < 4; ++r) {
      const int row = quad * 4 + r;
      pp[row * 17 + n]       = acc0[r];
      pp[272 + row * 17 + n] = acc1[r];
    }
  }
  __syncthreads();
  if (wv == 0) {
    #pragma unroll
    for (int r = 0; r < 4; ++r) {
      const int row = quad * 4 + r;
      const float v0 = ((acc0[r] + ps[row * 17 + n]) + ps[544 + row * 17 + n])
                       + ps[1088 + row * 17 + n];
      const float v1 = ((acc1[r] + ps[272 + row * 17 + n]) + ps[816 + row * 17 + n])
                       + ps[1360 + row * 17 + n];
      const long i0 = (long)(r0 + row) * CD + n;
      zc[i0]      = v0;
      zc[i0 + 16] = v1;
      unsigned short h, l;
      split_bf16(-2.f * v0, h, l); zh[i0] = h;      zl[i0] = l;
      split_bf16(-2.f * v1, h, l); zh[i0 + 16] = h; zl[i0 + 16] = l;
    }
  }
}

// ---------------- MFMA approx distances + per-chunk min ----------------
// 2 chunks staged per block (32 KB) behind ONE barrier; A fragments reused.
__global__ __launch_bounds__(256) void k_argmin(
    const unsigned short* __restrict__ zh, const unsigned short* __restrict__ zl,
    const unsigned short* __restrict__ ch, const unsigned short* __restrict__ cl,
    const float* __restrict__ cnorm,
    float* __restrict__ pd) {
  __shared__ __align__(16) unsigned short chs[2][CPC * CD];   // 16 KB
  __shared__ __align__(16) unsigned short cls[2][CPC * CD];   // 16 KB
  const int pb   = blockIdx.x & (M / PTB - 1);   // 0..63
  const int cp   = blockIdx.x >> 6;              // 0..31 chunk-pair
  const int cid0 = cp * 2;
  const int lane = threadIdx.x & 63;
  const int wv   = threadIdx.x >> 6;
  const int col  = lane & 15;
  const int quad = lane >> 4;
  const int p0   = pb * PTB + wv * 64;

  const char* chg = (const char*)ch + (long)cid0 * (CPC * CD * 2);
  const char* clg = (const char*)cl + (long)cid0 * (CPC * CD * 2);
  #pragma unroll
  for (int s = 0; s < 4; ++s) {
    const int lo = s * 4096 + wv * 1024;
    gload_lds16(chg + lo + lane * 16, (char*)chs + lo);
    gload_lds16(clg + lo + lane * 16, (char*)cls + lo);
  }

  short8 Ah[4], Al[4];
  #pragma unroll
  for (int s = 0; s < 4; ++s) {
    Ah[s] = *(const short8*)(zh + (long)(p0 + s * 16 + col) * CD + quad * 8);
    Al[s] = *(const short8*)(zl + (long)(p0 + s * 16 + col) * CD + quad * 8);
  }

  float cnv[2][8];
  #pragma unroll
  for (int c2 = 0; c2 < 2; ++c2) {
    const int jb = (cid0 + c2) * CPC;
    #pragma unroll
    for (int tt = 0; tt < 8; ++tt) cnv[c2][tt] = cnorm[jb + tt * 16 + col];
  }

  __syncthreads();   // drains global_load_lds (vmcnt) + A/cnv loads

  #pragma unroll
  for (int c2 = 0; c2 < 2; ++c2) {
    float bd[4][4];
    #pragma unroll
    for (int s = 0; s < 4; ++s)
      #pragma unroll
      for (int r = 0; r < 4; ++r) bd[s][r] = 1e30f;

    #pragma unroll
    for (int tt = 0; tt < 8; ++tt) {           // 8 tiles of 16 codes from LDS
      const short8 Bh = *(const short8*)(&chs[c2][(tt * 16 + col) * CD + quad * 8]);
      const short8 Bl = *(const short8*)(&cls[c2][(tt * 16 + col) * CD + quad * 8]);
      const f32x4 c4 = {cnv[c2][tt], cnv[c2][tt], cnv[c2][tt], cnv[c2][tt]};
      #pragma unroll
      for (int s = 0; s < 4; ++s) {
        f32x4 g = __builtin_amdgcn_mfma_f32_16x16x32_bf16(Ah[s], Bh, c4, 0, 0, 0);
        g = __builtin_amdgcn_mfma_f32_16x16x32_bf16(Ah[s], Bl, g, 0, 0, 0);
        g = __builtin_amdgcn_mfma_f32_16x16x32_bf16(Al[s], Bh, g, 0, 0, 0);
        #pragma unroll
        for (int r = 0; r < 4; ++r) bd[s][r] = fminf(bd[s][r], g[r]);
      }
    }

    #pragma unroll
    for (int mm = 1; mm <= 8; mm <<= 1) {
      #pragma unroll
      for (int s = 0; s < 4; ++s)
        #pragma unroll
        for (int r = 0; r < 4; ++r)
          bd[s][r] = fminf(bd[s][r], __shfl_xor(bd[s][r], mm, 64));
    }
    if (col == 0) {
      #pragma unroll
      for (int s = 0; s < 4; ++s)
        #pragma unroll
        for (int r = 0; r < 4; ++r) {
          const int pA = p0 + s * 16 + quad * 4 + r;
          pd[(long)pA * SCH + cid0 + c2] = bd[s][r];
        }
    }
  }
}

// ---------------- exact-fp32 rescue over transposed codebook (coalesced scan) --------
__global__ __launch_bounds__(256) void k_rescue(
    const float* __restrict__ zc, const float* __restrict__ cb,
    const float* __restrict__ cbT, const float* __restrict__ cnorm,
    const float* __restrict__ pd,
    float* __restrict__ zq, unsigned short* __restrict__ zqh,
    unsigned short* __restrict__ zql, float* __restrict__ lpart) {
  const int lane = threadIdx.x & 63;
  const int wv   = threadIdx.x >> 6;
  const int p    = blockIdx.x * 4 + wv;

  const float m = pd[(long)p * SCH + lane];
  float dstar = m;
  #pragma unroll
  for (int mm = 1; mm <= 32; mm <<= 1) dstar = fminf(dstar, __shfl_xor(dstar, mm, 64));
  unsigned long long mask = __ballot(m <= dstar + MARGIN);

  float zr[CD];
  {
    const float4* z4 = (const float4*)(zc + (long)p * CD);
    #pragma unroll
    for (int q = 0; q < 8; ++q) {
      float4 v = z4[q];
      zr[4 * q + 0] = v.x; zr[4 * q + 1] = v.y; zr[4 * q + 2] = v.z; zr[4 * q + 3] = v.w;
    }
  }

  float bd = 1e30f;
  int   bj = 0x7fffffff;
  while (mask) {
    const int c = (int)__builtin_ctzll(mask);
    mask &= mask - 1;
    const int j0 = c * CPC + 2 * lane;
    const float* cp = cbT + j0;
    float acc0 = 0.f, acc1 = 0.f;
    #pragma unroll
    for (int k = 0; k < CD; ++k) {
      const float2 cv = *(const float2*)(cp + (long)k * NE);
      acc0 = fmaf(zr[k], cv.x, acc0);
      acc1 = fmaf(zr[k], cv.y, acc1);
    }
    const float2 cn = *(const float2*)(cnorm + j0);
    const float d0 = fmaf(-2.f, acc0, cn.x);
    const float d1 = fmaf(-2.f, acc1, cn.y);
    if (d0 < bd) { bd = d0; bj = j0; }
    if (d1 < bd) { bd = d1; bj = j0 + 1; }
  }
  #pragma unroll
  for (int mm = 1; mm <= 32; mm <<= 1) {
    const float od = __shfl_xor(bd, mm, 64);
    const int   oj = __shfl_xor(bj, mm, 64);
    if (od < bd || (od == bd && oj < bj)) { bd = od; bj = oj; }
  }

  float ls = 0.f;
  if (lane < 32) {
    const float cv = cb[(long)bj * CD + lane];
    const float zv = zc[(long)p * CD + lane];
    zq[(long)p * CD + lane] = cv;
    unsigned short hh, ll;
    split_bf16(cv, hh, ll);
    zqh[(long)p * CD + lane] = hh;
    zql[(long)p * CD + lane] = ll;
    const float df = cv - zv;
    ls = df * df;
  }
  #pragma unroll
  for (int mm = 1; mm <= 32; mm <<= 1) ls += __shfl_xor(ls, mm, 64);
  if (lane == 0) lpart[p] = ls;
}

// ---------------- out = z_q @ W_expand + b_expand via split-bf16 MFMA ----------------
// 3072 blocks: block = 16 rows x 256 cols (4 waves x 4 tiles), ONE LDS park +
// barrier, then per-row 1-KB contiguous float4 stores.
__global__ __launch_bounds__(256) void k_expand(
    const unsigned short* __restrict__ zqh, const unsigned short* __restrict__ zql,
    const unsigned short* __restrict__ WeTh, const unsigned short* __restrict__ WeTl,
    const float* __restrict__ be,
    const float* __restrict__ lpart,
    float* __restrict__ out,
    float* __restrict__ out_loss) {
  __shared__ float ob[16][260];
  __shared__ double redd[4];
  const int t = threadIdx.x;
  if (blockIdx.x == 3072) {
    double v = 0.0;
    for (int k = t; k < M; k += 256) v += (double)lpart[k];
    #pragma unroll
    for (int mm = 1; mm <= 32; mm <<= 1) v += __shfl_xor(v, mm, 64);
    if ((t & 63) == 0) redd[t >> 6] = v;
    __syncthreads();
    if (t == 0)
      out_loss[0] = (float)(3.0 * (redd[0] + redd[1] + redd[2] + redd[3]) / (double)(M * CD));
    return;
  }
  const int lane = t & 63;
  const int wv   = t >> 6;
  const int col  = lane & 15;
  const int quad = lane >> 4;
  const int rb   = blockIdx.x & 1023;      // row-block 0..1023
  const int cg   = blockIdx.x >> 10;       // col-group 0..2
  const int r0   = rb * 16;

  const short8 Ah = *(const short8*)(zqh + (long)(r0 + col) * CD + quad * 8);
  const short8 Al = *(const short8*)(zql + (long)(r0 + col) * CD + quad * 8);

  #pragma unroll
  for (int tt = 0; tt < 4; ++tt) {
    const int n0 = cg * 256 + wv * 64 + tt * 16;
    const short8 Bh = *(const short8*)(WeTh + (long)(n0 + col) * CD + quad * 8);
    const short8 Bl = *(const short8*)(WeTl + (long)(n0 + col) * CD + quad * 8);
    const float bv = be[n0 + col];
    const f32x4 c4 = {bv, bv, bv, bv};
    f32x4 g = __builtin_amdgcn_mfma_f32_16x16x32_bf16(Ah, Bh, c4, 0, 0, 0);
    g = __builtin_amdgcn_mfma_f32_16x16x32_bf16(Ah, Bl, g, 0, 0, 0);
    g = __builtin_amdgcn_mfma_f32_16x16x32_bf16(Al, Bh, g, 0, 0, 0);
    #pragma unroll
    for (int r = 0; r < 4; ++r)
      ob[quad * 4 + r][wv * 64 + tt * 16 + col] = g[r];
  }
  __syncthreads();
  #pragma unroll
  for (int i = 0; i < 4; ++i) {
    const int f   = t + i * 256;             // 0..1023 float4 slots
    const int row = f >> 6;                  // 0..15
    const int c4  = f & 63;                  // 0..63
    *(float4*)(out + (long)(r0 + row) * CIN + cg * 256 + c4 * 4) =
        *(const float4*)(&ob[row][c4 * 4]);
  }
}

extern "C" void kernel_launch(void* const* d_in, const int* in_sizes, int n_in,
                              void* d_out, int out_size, void* d_ws, size_t ws_size,
                              hipStream_t stream) {
  const float* z   = (const float*)d_in[0];
  const float* emb = (const float*)d_in[1];
  const float* Wc  = (const float*)d_in[2];
  const float* bc  = (const float*)d_in[3];
  const float* Wct = (const float*)d_in[4];
  const float* bct = (const float*)d_in[5];
  const float* We  = (const float*)d_in[6];
  const float* be  = (const float*)d_in[7];
  float* out = (float*)d_out;

  float* cb    = (float*)d_ws;              // NE*CD        = 262144 f
  float* cnorm = cb + NE * CD;              // NE           = 8192 f
  float* zc    = cnorm + NE;                // M*CD         = 524288 f
  float* zq    = zc + M * CD;               // M*CD         = 524288 f
  float* pd    = zq + M * CD;               // M*SCH        = 1048576 f
  float* lpart = pd + (long)M * SCH;        // M            = 16384 f
  unsigned short* zh   = (unsigned short*)(lpart + M);   // M*CD ush
  unsigned short* zl   = zh + M * CD;
  unsigned short* ch   = zl + M * CD;       // NE*CD ush
  unsigned short* cl   = ch + NE * CD;
  unsigned short* zqh  = cl + NE * CD;      // M*CD ush
  unsigned short* zql  = zqh + M * CD;
  unsigned short* WeTh = zql + M * CD;      // CIN*CD ush
  unsigned short* WeTl = WeTh + CIN * CD;
  float* cbT = (float*)(WeTl + CIN * CD);   // CD*NE = 262144 f

  k_main<<<2048, 256, 0, stream>>>(z, Wc, bc, emb, Wct, bct, We,
                                   zc, zh, zl, cb, cbT, cnorm, ch, cl, WeTh, WeTl);
  k_argmin<<<(M / PTB) * (SCH / 2), 256, 0, stream>>>(zh, zl, ch, cl, cnorm, pd);
  k_rescue<<<M / 4, 256, 0, stream>>>(zc, cb, cbT, cnorm, pd, zq, zqh, zql, lpart);
  k_expand<<<3072 + 1, 256, 0, stream>>>(zqh, zql, WeTh, WeTl, be, lpart,
                                         out, out + (long)M * CIN);
}